// Round 10
// baseline (85.995 us; speedup 1.0000x reference)
//
#include <hip/hip_runtime.h>
#include <math.h>

#define BEV_H 200
#define BEV_W 200
#define NPIX (BEV_H * BEV_W)
#define TILE 8
#define NT 25           // 200/8
#define NB 2
#define T_DEAD 1e-10f
#define SEGCAP 512      // per-wave segment capacity (G/4 rounded to 512)
#define KC 32           // staging chunk per wave
#define MWORDS 64       // 2048 bits per tile mask (covers G <= 2048)
#define NLOG255 (-5.5412635f)   // -ln(255)

// round-to-nearest bf16 pack of two floats into one uint (lo=x, hi=y)
__device__ __forceinline__ unsigned pk2bf(float x, float y)
{
    unsigned ux = __float_as_uint(x), uy = __float_as_uint(y);
    ux = ux + 0x7fffu + ((ux >> 16) & 1u);
    uy = uy + 0x7fffu + ((uy >> 16) & 1u);
    return (ux >> 16) | (uy & 0xffff0000u);
}

// Kernel A: per-gaussian params (once!) + bitmask binning.
// R9 recomputed the bbox test per (tile,gaussian) = 2.5M times with scattered
// loads + transcendentals (~15 us chip-wide). Here: 4000 threads, each sets
// bit g in the masks of the ~12 tiles its bbox overlaps (atomicOr, low
// contention). Superset-conservative tile range is CORRECT: extra entries
// composite to alpha=0 via the per-pixel power test.
__global__ __launch_bounds__(256) void bin_kernel(
    const float* __restrict__ means3D, const float* __restrict__ cov3D,
    const float* __restrict__ opac, float4* __restrict__ params,
    unsigned* __restrict__ masks, int G, int n)
{
    const int idx = blockIdx.x * 256 + threadIdx.x;
    if (idx >= n) return;
    const int b = idx / G;
    const int g = idx - b * G;
    const float x = means3D[idx * 3 + 0], y = means3D[idx * 3 + 1];
    const float sxx = cov3D[idx * 6 + 0], sxy = cov3D[idx * 6 + 1],
                syy = cov3D[idx * 6 + 3];
    const float op = opac[idx];
    const float u = -2.0f * y + 100.0f;   // sh = BEV_H/H_METERS = 2
    const float v = -2.0f * x + 100.0f;
    const float c00 = 4.0f * syy + 0.3f;
    const float c01 = 4.0f * sxy;
    const float c11 = 4.0f * sxx + 0.3f;
    const float det = c00 * c11 - c01 * c01;
    if (!(op > 0.05f && det > 0.0f)) return;   // bit never set; params unread
    const float inv = 1.0f / det;
    const float L = __logf(255.0f * op);       // > 0 since op > 0.05
    params[(size_t)idx * 2 + 0] = make_float4(u, v, -0.5f * c11 * inv, c01 * inv);
    params[(size_t)idx * 2 + 1] = make_float4(-0.5f * c00 * inv, L + NLOG255,
                                              0.0f, 0.0f);   // ln(op) = L - ln255
    const float ru = sqrtf(2.0f * L * c00) + 0.01f;
    const float rv = sqrtf(2.0f * L * c11) + 0.01f;
    // tile ti covers rows [8ti, 8ti+7]; overlap [u-ru, u+ru] (eps = superset)
    const int ti0 = max(0, (int)ceilf((u - ru - 7.001f) * 0.125f));
    const int ti1 = min(NT - 1, (int)floorf((u + ru + 0.001f) * 0.125f));
    const int tj0 = max(0, (int)ceilf((v - rv - 7.001f) * 0.125f));
    const int tj1 = min(NT - 1, (int)floorf((v + rv + 0.001f) * 0.125f));
    const int word = g >> 5;
    const unsigned bit = 1u << (g & 31);
    for (int ti = ti0; ti <= ti1; ++ti)
        for (int tj = tj0; tj <= tj1; ++tj)
            atomicOr(&masks[(size_t)(((b * NT) + ti) * NT + tj) * MWORDS + word],
                     bit);
}

// Kernel B: 4 waves per 8x8 tile, G in 4 segments of 512 (compositing
// monoid: out = a0 + T0*(a1 + T1*(a2 + T2*a3))). The R9 scan (8 rounds x
// scattered loads + transcendentals per wave) is replaced by reading 16
// mask dwords and iterating set bits (g-ordered for free).
__global__ __launch_bounds__(256, 5) void render_tile_kernel(
    const float* __restrict__ features, const float4* __restrict__ params,
    const unsigned* __restrict__ masks, const float* __restrict__ opac,
    float* __restrict__ out, int G)
{
    // layout: glist u16[4][512] (4096) | plA f4[4][32] (2048 @4096) |
    //         plB f2[4][32] (1024 @6144) | flq u4[4][32][4] (8192 @7168)
    // combine overlay (barrier-guarded): xch f32[2][64][33] (16896 @0)
    __shared__ __align__(16) unsigned char smem[16896];
    unsigned short* glist = (unsigned short*)smem;
    float4* plA = (float4*)(smem + 4096);
    float2* plB = (float2*)(smem + 6144);
    uint4*  flq = (uint4*)(smem + 7168);
    float*  xch = (float*)smem;

    const int tid  = threadIdx.x;
    const int lane = tid & 63;
    const int w    = tid >> 6;           // wave id = G-segment id
    const int b  = blockIdx.z;
    const int tj = blockIdx.x;
    const int ti = blockIdx.y;
    const int j = tj * TILE + (lane & 7);
    const int i = ti * TILE + (lane >> 3);
    const float fi = (float)i, fj = (float)j;
    const int gbase = b * G;

    // ---- build kept list from tile bitmask (order-preserving, no ballot) ----
    const size_t mbase = (size_t)(((b * NT) + ti) * NT + tj) * MWORDS + w * 16;
    const unsigned m = (lane < 16) ? masks[mbase + lane] : 0u;
    int tot = 0;
#pragma unroll
    for (int r = 0; r < 8; ++r) {
        const unsigned lo = __shfl(m, 2 * r);
        const unsigned hi = __shfl(m, 2 * r + 1);
        const unsigned long long mm = ((unsigned long long)hi << 32) | lo;
        if ((mm >> lane) & 1ull) {
            const int pre = (int)__popcll(mm & ((1ull << lane) - 1ull));
            glist[w * SEGCAP + tot + pre] =
                (unsigned short)(w * 512 + r * 64 + lane);
        }
        tot += (int)__popcll(mm);
    }

    // ---- wave-local chunked stage + branchless composite ----
    float acc[32];
#pragma unroll
    for (int d = 0; d < 32; ++d) acc[d] = 0.0f;
    float T = 1.0f;   // within-segment transmittance

    for (int k0 = 0; k0 < tot; k0 += KC) {
        if (!__any(T >= T_DEAD)) break;
        const int nk = min(KC, tot - k0);

        // stage params: gather 2 float4 per kept entry from ws
        if (lane < nk) {
            const int g = glist[w * SEGCAP + k0 + lane];
            const float4* pp = params + (size_t)(gbase + g) * 2;
            const float4 a = pp[0];
            const float4 c = pp[1];
            plA[w * KC + lane] = a;
            plB[w * KC + lane] = make_float2(c.x, c.y);
        }
        // stage features: entry e, quarter q (8 floats -> 4 bf16-pairs)
        for (int idx = lane; idx < nk * 4; idx += 64) {
            const int e = idx >> 2, q = idx & 3;
            const int g = glist[w * SEGCAP + k0 + e];
            const float4* fp =
                (const float4*)(features + (size_t)(gbase + g) * 32) + q * 2;
            const float4 A = fp[0], Bq = fp[1];
            flq[(w * KC + e) * 4 + q] =
                make_uint4(pk2bf(A.x, A.y), pk2bf(A.z, A.w),
                           pk2bf(Bq.x, Bq.y), pk2bf(Bq.z, Bq.w));
        }
        // same-wave LDS ordering: compiler inserts lgkmcnt waits

        for (int k = 0; k < nk; ++k) {
            const float4 pA = plA[w * KC + k];
            const float2 pB = plB[w * KC + k];
            const float du = pA.x - fi;
            const float dv = pA.y - fj;
            const float power = pA.z * du * du + pB.x * dv * dv + pA.w * du * dv;
            const float powb = power + pB.y;          // + ln(op)
            float alpha = fminf(0.99f, __expf(powb));
            const bool ok = (powb >= NLOG255) && (power <= 0.0f);
            alpha = ok ? alpha : 0.0f;
            const float wgt = alpha * T;
            T *= 1.0f - alpha;
#pragma unroll
            for (int q = 0; q < 4; ++q) {
                const uint4 uq = flq[(w * KC + k) * 4 + q];
                const unsigned uu[4] = {uq.x, uq.y, uq.z, uq.w};
#pragma unroll
                for (int c = 0; c < 4; ++c) {
                    const float lof = __uint_as_float(uu[c] << 16);
                    const float hif = __uint_as_float(uu[c] & 0xffff0000u);
                    acc[q * 8 + c * 2 + 0] = fmaf(wgt, lof, acc[q * 8 + c * 2 + 0]);
                    acc[q * 8 + c * 2 + 1] = fmaf(wgt, hif, acc[q * 8 + c * 2 + 1]);
                }
            }
        }
    }

    // ---- hierarchical combine on xch overlay (barrier-guarded) ----
    __syncthreads();   // all waves done with glist/plA/plB/flq
    if (w == 1 || w == 3) {
        float* row = xch + (((w - 1) >> 1) * 64 + lane) * 33;
#pragma unroll
        for (int d = 0; d < 32; ++d) row[d] = acc[d];
        row[32] = T;
    }
    __syncthreads();
    if (w == 0 || w == 2) {
        const float* row = xch + ((w >> 1) * 64 + lane) * 33;
        const float Tn = row[32];
#pragma unroll
        for (int d = 0; d < 32; ++d) acc[d] = fmaf(T, row[d], acc[d]);
        T *= Tn;
    }
    __syncthreads();
    if (w == 2) {
        float* row = xch + lane * 33;
#pragma unroll
        for (int d = 0; d < 32; ++d) row[d] = acc[d];
        row[32] = T;
    }
    __syncthreads();

    if (w == 0) {
        const float* row = xch + lane * 33;
#pragma unroll
        for (int d = 0; d < 32; ++d) acc[d] = fmaf(T, row[d], acc[d]);

        const int p = i * BEV_W + j;   // 200 % 8 == 0: always in range
        float* ob = out + (size_t)b * 32 * NPIX + p;
#pragma unroll
        for (int d = 0; d < 32; ++d) ob[(size_t)d * NPIX] = acc[d];
    }

    // ---- num_gaussians = sum(op > 0.05)/B on block 0 wave 1 (hidden tail) ----
    if (w == 1 && blockIdx.x == 0 && blockIdx.y == 0 && blockIdx.z == 0) {
        const float4* o4 = (const float4*)opac;
        const int n4 = (NB * G) >> 2;
        float s = 0.0f;
        for (int idx = lane; idx < n4; idx += 64) {
            const float4 o = o4[idx];
            s += (o.x > 0.05f ? 1.0f : 0.0f) + (o.y > 0.05f ? 1.0f : 0.0f) +
                 (o.z > 0.05f ? 1.0f : 0.0f) + (o.w > 0.05f ? 1.0f : 0.0f);
        }
#pragma unroll
        for (int off = 32; off > 0; off >>= 1) s += __shfl_down(s, off);
        if (lane == 0) out[NB * 32 * NPIX] = s * (1.0f / NB);
    }
}

extern "C" void kernel_launch(void* const* d_in, const int* in_sizes, int n_in,
                              void* d_out, int out_size, void* d_ws, size_t ws_size,
                              hipStream_t stream)
{
    const float* features = (const float*)d_in[0];
    const float* means3D  = (const float*)d_in[1];
    const float* cov3D    = (const float*)d_in[2];
    const float* opac     = (const float*)d_in[3];
    float* out = (float*)d_out;

    const int G = in_sizes[3] / NB;   // opacities is (B, G, 1)
    const int n = NB * G;

    const size_t mask_bytes = (size_t)NB * NT * NT * MWORDS * 4;   // 320 KB
    unsigned* masks = (unsigned*)d_ws;
    float4* params  = (float4*)((char*)d_ws + mask_bytes);

    hipMemsetAsync(masks, 0, mask_bytes, stream);

    bin_kernel<<<(n + 255) / 256, 256, 0, stream>>>(
        means3D, cov3D, opac, params, masks, G, n);

    dim3 grid(NT, NT, NB);
    render_tile_kernel<<<grid, 256, 0, stream>>>(features, params, masks, opac,
                                                 out, G);
}

// Round 12
// 81.309 us; speedup vs baseline: 1.0576x; 1.0576x over previous
//
#include <hip/hip_runtime.h>
#include <math.h>

#define BEV_H 200
#define BEV_W 200
#define NPIX (BEV_H * BEV_W)
#define TILE 8
#define NT 25           // 200/8
#define NB 2
#define T_DEAD 1e-10f
#define SEGCAP 512      // per-wave segment capacity (G/4 = 500)
#define PCAP 128        // params parked at scan time (multiple of KC)
#define KC 32           // feature-staging chunk per wave
#define NLOG255 (-5.5412635f)   // -ln(255)

// round-to-nearest bf16 pack of two floats into one uint (lo=x, hi=y)
__device__ __forceinline__ unsigned pk2bf(float x, float y)
{
    unsigned ux = __float_as_uint(x), uy = __float_as_uint(y);
    ux = ux + 0x7fffu + ((ux >> 16) & 1u);
    uy = uy + 0x7fffu + ((uy >> 16) & 1u);
    return (ux >> 16) | (uy & 0xffff0000u);
}

// Fused renderer R12 (= R11 with the overlay-guard barrier restored):
// R11 crashed because waves 1-3 wrote combine partials over glist/plA
// BEFORE a barrier, while other waves were still compositing from those
// buffers -> garbage u16 gaussian indices -> OOB feature reads -> abort.
// The overlay needs a GUARD barrier before any write. Combine is now 2
// barriers (guard + publish), down from R9's 4 sync points.
//  - 4 waves per 8x8 tile, G in 4 segments (compositing monoid:
//    out = a0 + T0*a1 + T0T1*a2 + T0T1T2*a3).
//  - scan: inline precompute, 2-deep load pipeline, SQRT-FREE tile test,
//    params parked to LDS from registers at ballot time.
//  - composite: branchless, bf16 features in LDS.
//  - count folded into block 0 wave 1 post-barrier.
__global__ __launch_bounds__(256, 5) void render_fused_kernel(
    const float* __restrict__ features, const float* __restrict__ means3D,
    const float* __restrict__ cov3D, const float* __restrict__ opac,
    float* __restrict__ out, int G)
{
    // glist u16[4][512] @0 (4096) | plA f4[4][128] @4096 (8192) |
    // plB f2[4][128] @12288 (4096) | flq u4[4][32][4] @16384 (8192) = 24576 B
    // combine overlay (GUARD-barrier-protected): xch f32[3][64][17] @0 (13056)
    __shared__ __align__(16) unsigned char smem[24576];
    unsigned short* glist = (unsigned short*)smem;
    float4* plA = (float4*)(smem + 4096);
    float2* plB = (float2*)(smem + 12288);
    uint4*  flq = (uint4*)(smem + 16384);
    float*  xch = (float*)smem;

    const int tid  = threadIdx.x;
    const int lane = tid & 63;
    const int w    = tid >> 6;           // wave id = G-segment id
    const int b  = blockIdx.z;
    const int tj = blockIdx.x;
    const int ti = blockIdx.y;
    const int j = tj * TILE + (lane & 7);
    const int i = ti * TILE + (lane >> 3);
    const float fi = (float)i, fj = (float)j;
    const float ti_lo = (float)(ti * TILE), ti_hi = ti_lo + (TILE - 1);
    const float tj_lo = (float)(tj * TILE), tj_hi = tj_lo + (TILE - 1);
    const int gbase = b * G;
    const int g_lo = (w * G) >> 2;
    const int g_hi = ((w + 1) * G) >> 2;
    const int rounds = (g_hi - g_lo + 63) >> 6;

    // ---- scan: inline precompute, 2-deep pipelined loads, sqrt-free test,
    //      ballot compaction, params parked from registers ----
    int tot = 0;
    {
        int gg = min(g_lo + lane, g_hi - 1);
        size_t gi = (size_t)(gbase + gg);
        float x0 = means3D[gi * 3 + 0], y0 = means3D[gi * 3 + 1];
        float s0 = cov3D[gi * 6 + 0], s1 = cov3D[gi * 6 + 1], s3 = cov3D[gi * 6 + 3];
        float o0 = opac[gi];
        for (int r = 0; r < rounds; ++r) {
            float x1 = 0.f, y1 = 0.f, t0 = 0.f, t1 = 0.f, t3 = 0.f, o1 = 0.f;
            if (r + 1 < rounds) {   // prefetch next round (wave-uniform branch)
                const int gn = min(g_lo + (r + 1) * 64 + lane, g_hi - 1);
                const size_t gni = (size_t)(gbase + gn);
                x1 = means3D[gni * 3 + 0]; y1 = means3D[gni * 3 + 1];
                t0 = cov3D[gni * 6 + 0];   t1 = cov3D[gni * 6 + 1];
                t3 = cov3D[gni * 6 + 3];   o1 = opac[gni];
            }
            const int g = g_lo + r * 64 + lane;
            const float u = -2.0f * y0 + 100.0f;   // sh = BEV_H/H_METERS = 2
            const float v = -2.0f * x0 + 100.0f;
            const float c00 = 4.0f * s3 + 0.3f;
            const float c01 = 4.0f * s1;
            const float c11 = 4.0f * s0 + 0.3f;
            const float det = c00 * c11 - c01 * c01;
            bool keep = false;
            float L = 0.0f;
            if (o0 > 0.05f && det > 0.0f && g < g_hi) {
                L = __logf(255.0f * o0);           // > 0 since op > 0.05
                const float tl2 = 2.0f * L;
                // clamp distance from tile interval to center; ellipse
                // u-extent is exactly sqrt(2L*c00): compare squared.
                const float dut = fmaxf(fmaxf(ti_lo - u, u - ti_hi), 0.0f);
                const float dvt = fmaxf(fmaxf(tj_lo - v, v - tj_hi), 0.0f);
                keep = (dut * dut <= tl2 * c00 + 1e-4f) &&
                       (dvt * dvt <= tl2 * c11 + 1e-4f);
            }
            const unsigned long long bal = __ballot(keep);
            if (keep) {
                const int slot = tot + (int)__popcll(bal & ((1ull << lane) - 1ull));
                glist[w * SEGCAP + slot] = (unsigned short)g;
                if (slot < PCAP) {
                    const float inv = 1.0f / det;
                    plA[w * PCAP + slot] =
                        make_float4(u, v, -0.5f * c11 * inv, c01 * inv);
                    plB[w * PCAP + slot] = make_float2(-0.5f * c00 * inv,
                                                       L + NLOG255);  // ln(op)
                }
            }
            tot += (int)__popcll(bal);
            x0 = x1; y0 = y1; s0 = t0; s1 = t1; s3 = t3; o0 = o1;
        }
    }

    // ---- wave-local: stage features per chunk + branchless composite ----
    float acc[32];
#pragma unroll
    for (int d = 0; d < 32; ++d) acc[d] = 0.0f;
    float T = 1.0f;   // within-segment transmittance

    for (int k0 = 0; k0 < tot; k0 += KC) {
        if (!__any(T >= T_DEAD)) break;
        const int nk = min(KC, tot - k0);

        // overflow chunks (k0 >= PCAP; ~never at ~11 kept/wave): recompute
        // params into slots [0,KC)
        if (k0 >= PCAP && lane < nk) {
            const int g = glist[w * SEGCAP + k0 + lane];
            const size_t gi = (size_t)(gbase + g);
            const float x = means3D[gi * 3 + 0], y = means3D[gi * 3 + 1];
            const float sxx = cov3D[gi * 6 + 0], sxy = cov3D[gi * 6 + 1],
                        syy = cov3D[gi * 6 + 3];
            const float op = opac[gi];
            const float u = -2.0f * y + 100.0f;
            const float v = -2.0f * x + 100.0f;
            const float c00 = 4.0f * syy + 0.3f;
            const float c01 = 4.0f * sxy;
            const float c11 = 4.0f * sxx + 0.3f;
            const float inv = 1.0f / (c00 * c11 - c01 * c01);
            plA[w * PCAP + lane] = make_float4(u, v, -0.5f * c11 * inv, c01 * inv);
            plB[w * PCAP + lane] = make_float2(-0.5f * c00 * inv, __logf(op));
        }
        // stage features: entry e, quarter q (8 floats -> 4 bf16-pairs)
        for (int idx = lane; idx < nk * 4; idx += 64) {
            const int e = idx >> 2, q = idx & 3;
            const int g = glist[w * SEGCAP + k0 + e];
            const float4* fp =
                (const float4*)(features + (size_t)(gbase + g) * 32) + q * 2;
            const float4 A = fp[0], Bq = fp[1];
            flq[(w * KC + e) * 4 + q] =
                make_uint4(pk2bf(A.x, A.y), pk2bf(A.z, A.w),
                           pk2bf(Bq.x, Bq.y), pk2bf(Bq.z, Bq.w));
        }
        // same-wave LDS ordering: compiler inserts lgkmcnt waits

        const int pbase = w * PCAP + ((k0 < PCAP) ? k0 : 0);
        for (int k = 0; k < nk; ++k) {
            const float4 pA = plA[pbase + k];
            const float2 pB = plB[pbase + k];
            const float du = pA.x - fi;
            const float dv = pA.y - fj;
            const float power = pA.z * du * du + pB.x * dv * dv + pA.w * du * dv;
            const float powb = power + pB.y;          // + ln(op)
            float alpha = fminf(0.99f, __expf(powb));
            const bool ok = (powb >= NLOG255) && (power <= 0.0f);
            alpha = ok ? alpha : 0.0f;
            const float wgt = alpha * T;
            T *= 1.0f - alpha;
#pragma unroll
            for (int q = 0; q < 4; ++q) {
                const uint4 uq = flq[(w * KC + k) * 4 + q];
                const unsigned uu[4] = {uq.x, uq.y, uq.z, uq.w};
#pragma unroll
                for (int c = 0; c < 4; ++c) {
                    const float lof = __uint_as_float(uu[c] << 16);
                    const float hif = __uint_as_float(uu[c] & 0xffff0000u);
                    acc[q * 8 + c * 2 + 0] = fmaf(wgt, lof, acc[q * 8 + c * 2 + 0]);
                    acc[q * 8 + c * 2 + 1] = fmaf(wgt, hif, acc[q * 8 + c * 2 + 1]);
                }
            }
        }
    }

    // ---- combine: GUARD barrier, publish partials, PUBLISH barrier ----
    __syncthreads();   // guard: all waves done reading glist/plA/plB/flq
    if (w != 0) {
        float* row = xch + ((w - 1) * 64 + lane) * 17;
        unsigned* urow = (unsigned*)row;
#pragma unroll
        for (int c2 = 0; c2 < 16; ++c2)
            urow[c2] = pk2bf(acc[2 * c2], acc[2 * c2 + 1]);
        row[16] = T;
    }
    __syncthreads();   // publish

    if (w == 0) {
        float W = T;   // running prefix transmittance T0, T0T1, T0T1T2
#pragma unroll
        for (int r = 1; r <= 3; ++r) {
            const float* row = xch + ((r - 1) * 64 + lane) * 17;
            const unsigned* urow = (const unsigned*)row;
#pragma unroll
            for (int c2 = 0; c2 < 16; ++c2) {
                const unsigned uv = urow[c2];
                acc[2 * c2 + 0] = fmaf(W, __uint_as_float(uv << 16),
                                       acc[2 * c2 + 0]);
                acc[2 * c2 + 1] = fmaf(W, __uint_as_float(uv & 0xffff0000u),
                                       acc[2 * c2 + 1]);
            }
            W *= row[16];
        }

        const int p = i * BEV_W + j;   // 200 % 8 == 0: always in range
        float* ob = out + (size_t)b * 32 * NPIX + p;
#pragma unroll
        for (int d = 0; d < 32; ++d) ob[(size_t)d * NPIX] = acc[d];
    }

    // ---- num_gaussians = sum(op > 0.05)/B on block 0 wave 1 (hidden tail) ----
    if (w == 1 && blockIdx.x == 0 && blockIdx.y == 0 && blockIdx.z == 0) {
        const float4* o4 = (const float4*)opac;
        const int n4 = (NB * G) >> 2;
        float s = 0.0f;
        for (int idx = lane; idx < n4; idx += 64) {
            const float4 o = o4[idx];
            s += (o.x > 0.05f ? 1.0f : 0.0f) + (o.y > 0.05f ? 1.0f : 0.0f) +
                 (o.z > 0.05f ? 1.0f : 0.0f) + (o.w > 0.05f ? 1.0f : 0.0f);
        }
#pragma unroll
        for (int off = 32; off > 0; off >>= 1) s += __shfl_down(s, off);
        if (lane == 0) out[NB * 32 * NPIX] = s * (1.0f / NB);
    }
}

extern "C" void kernel_launch(void* const* d_in, const int* in_sizes, int n_in,
                              void* d_out, int out_size, void* d_ws, size_t ws_size,
                              hipStream_t stream)
{
    const float* features = (const float*)d_in[0];
    const float* means3D  = (const float*)d_in[1];
    const float* cov3D    = (const float*)d_in[2];
    const float* opac     = (const float*)d_in[3];
    float* out = (float*)d_out;

    const int G = in_sizes[3] / NB;   // opacities is (B, G, 1)

    dim3 grid(NT, NT, NB);
    render_fused_kernel<<<grid, 256, 0, stream>>>(features, means3D, cov3D, opac,
                                                  out, G);
}